// Round 1
// baseline (391.279 us; speedup 1.0000x reference)
//
#include <hip/hip_runtime.h>
#include <hip/hip_bf16.h>

// RainReservoirEncoder: x_{t+1} = tanh(W x_t + w_in u_t), T=4096, hidden=16, B=8192.
// Latency-bound recurrence. Per wave: 16 batch chains via mfma_f32_16x16x16_bf16
// ping-pong identity: D frag (col=lane&15=batch, row=(lane>>4)*4+q=hidden) is
// bit-position-identical to the next step's B frag (n=lane&15, k=(lane>>4)*4+e).
// => zero cross-lane data movement per step.

#define B_SZ 8192
#define T_SZ 4096
#define H 16

typedef __attribute__((ext_vector_type(4))) short s16x4;
typedef __attribute__((ext_vector_type(4))) float f32x4;

static __device__ __forceinline__ short f2bf(float v) {
  __hip_bfloat16 h = __float2bfloat16(v);  // RNE
  return (short)__builtin_bit_cast(unsigned short, h);
}
static __device__ __forceinline__ float bf2f(short s) {
  unsigned short us = (unsigned short)s;
  __hip_bfloat16 h = __builtin_bit_cast(__hip_bfloat16, us);
  return __bfloat162float(h);
}

static __device__ __forceinline__ f32x4 mfma_bf16(s16x4 a, s16x4 b, f32x4 c) {
#if __has_builtin(__builtin_amdgcn_mfma_f32_16x16x16bf16_1k)
  return __builtin_amdgcn_mfma_f32_16x16x16bf16_1k(a, b, c, 0, 0, 0);
#else
  asm("v_mfma_f32_16x16x16_bf16 %0, %1, %2, %0" : "+v"(c) : "v"(a), "v"(b));
  return c;
#endif
}

__global__ __launch_bounds__(128) void rre_kernel(
    const float* __restrict__ rain,   // (B, T, 1) f32
    const float* __restrict__ w_in,   // (16, 1)  f32
    const float* __restrict__ w,      // (16, 16) f32
    float* __restrict__ out) {        // (B, 16)  f32
  const int lane = threadIdx.x & 63;
  const int wgrp = threadIdx.x >> 6;            // wave in block (0..1)
  const int col  = lane & 15;                   // batch slot within group
  const int grp  = lane >> 4;                   // k/row group (0..3)
  const int gid  = blockIdx.x * 2 + wgrp;       // 0..511
  const int b    = gid * 16 + col;

  const float KTANH = 2.8853900817779268f;      // 2/ln(2): exp2(KTANH*x) = e^{2x}

  // A = KTANH*W, split hi/lo in bf16 to cancel systematic W rounding.
  // Lane holds A[m=col][k=grp*4+e], e=0..3 -> row `col`, cols grp*4..grp*4+3.
  f32x4 wf = *(const f32x4*)(w + col * H + grp * 4);
  wf.x *= KTANH; wf.y *= KTANH; wf.z *= KTANH; wf.w *= KTANH;
  s16x4 whi, wlo;
  whi.x = f2bf(wf.x); wlo.x = f2bf(wf.x - bf2f(whi.x));
  whi.y = f2bf(wf.y); wlo.y = f2bf(wf.y - bf2f(whi.y));
  whi.z = f2bf(wf.z); wlo.z = f2bf(wf.z - bf2f(whi.z));
  whi.w = f2bf(wf.w); wlo.w = f2bf(wf.w - bf2f(whi.w));

  // C init term: lane needs w_in[i] for i = grp*4+q (pre-scaled by KTANH).
  f32x4 win = *(const f32x4*)(w_in + grp * 4);
  win.x *= KTANH; win.y *= KTANH; win.z *= KTANH; win.w *= KTANH;

  // Input stream for this lane's batch row. 4 u's per float4 chunk.
  const float* up = rain + (size_t)b * T_SZ;
  const int NC = T_SZ / 4;  // 1024 chunks

  auto LD = [&](int cc) -> f32x4 {
    cc = (cc < NC) ? cc : (NC - 1);             // clamp tail prefetch (in-bounds, unused)
    return *(const f32x4*)(up + cc * 4);
  };

  // 4-deep named prefetch ring (static indexing only — no scratch).
  f32x4 bufA = LD(0), bufB = LD(1), bufC = LD(2), bufD = LD(3);

  s16x4 xfrag = {0, 0, 0, 0};                   // x_0 = 0 (bf16 B-fragment)
  f32x4 xout = {0.f, 0.f, 0.f, 0.f};

#define STEP(u)                                                   \
  {                                                               \
    f32x4 acc;                                                    \
    acc.x = (u) * win.x; acc.y = (u) * win.y;                     \
    acc.z = (u) * win.z; acc.w = (u) * win.w;                     \
    acc = mfma_bf16(wlo, xfrag, acc);                             \
    acc = mfma_bf16(whi, xfrag, acc);                             \
    /* tanh(p) = 1 - 2/(1+e^{2p}); acc already = 2p/ln2 scaled */ \
    float e0 = __builtin_amdgcn_exp2f(acc.x);                     \
    float e1 = __builtin_amdgcn_exp2f(acc.y);                     \
    float e2 = __builtin_amdgcn_exp2f(acc.z);                     \
    float e3 = __builtin_amdgcn_exp2f(acc.w);                     \
    float r0 = __builtin_amdgcn_rcpf(e0 + 1.0f);                  \
    float r1 = __builtin_amdgcn_rcpf(e1 + 1.0f);                  \
    float r2 = __builtin_amdgcn_rcpf(e2 + 1.0f);                  \
    float r3 = __builtin_amdgcn_rcpf(e3 + 1.0f);                  \
    xout.x = __builtin_fmaf(-2.0f, r0, 1.0f);                     \
    xout.y = __builtin_fmaf(-2.0f, r1, 1.0f);                     \
    xout.z = __builtin_fmaf(-2.0f, r2, 1.0f);                     \
    xout.w = __builtin_fmaf(-2.0f, r3, 1.0f);                     \
    xfrag.x = f2bf(xout.x); xfrag.y = f2bf(xout.y);               \
    xfrag.z = f2bf(xout.z); xfrag.w = f2bf(xout.w);               \
  }

#define CHUNK(buf) { STEP(buf.x) STEP(buf.y) STEP(buf.z) STEP(buf.w) }

#pragma unroll 1
  for (int c = 0; c < NC; c += 4) {
    CHUNK(bufA); bufA = LD(c + 4);   // used 12 steps later (~covers HBM latency)
    CHUNK(bufB); bufB = LD(c + 5);
    CHUNK(bufC); bufC = LD(c + 6);
    CHUNK(bufD); bufD = LD(c + 7);
  }
#undef CHUNK
#undef STEP

  // Final state: lane holds x[b][grp*4+q] in xout (f32, pre-bf16-rounding).
  *(f32x4*)(out + (size_t)b * H + grp * 4) = xout;
}

extern "C" void kernel_launch(void* const* d_in, const int* in_sizes, int n_in,
                              void* d_out, int out_size, void* d_ws, size_t ws_size,
                              hipStream_t stream) {
  const float* rain = (const float*)d_in[0];
  const float* w_in = (const float*)d_in[1];
  const float* w    = (const float*)d_in[2];
  float* out = (float*)d_out;
  (void)in_sizes; (void)n_in; (void)out_size; (void)d_ws; (void)ws_size;

  // 512 waves (16 chains each) -> 256 blocks x 128 threads (2 waves/CU, own SIMDs).
  rre_kernel<<<B_SZ / 32, 128, 0, stream>>>(rain, w_in, w, out);
}